// Round 9
// baseline (166.456 us; speedup 1.0000x reference)
//
#include <hip/hip_runtime.h>
#include <hip/hip_bf16.h>

#define B_DIM 4096
#define M_DIM 4096
#define K_DIM 4096
#define NCODE 512

typedef __attribute__((ext_vector_type(4))) float f32x4;
typedef __attribute__((ext_vector_type(8))) short short8;

__device__ __forceinline__ unsigned short f2bf(float f) {
    union { float f; unsigned u; } c; c.f = f;
    unsigned u = c.u;
    return (unsigned short)((u + 0x7FFFu + ((u >> 16) & 1u)) >> 16);
}

// ---------------------------------------------------------------------------
// Prep: dequantize codes -> bf16 W [M_DIM][K_DIM] row-major (W-only now;
// A-conversion is fused into the GEMM staging).
// ---------------------------------------------------------------------------
__global__ __launch_bounds__(256) void prep_kernel(const int* __restrict__ Q,
                                                   const float* __restrict__ cb,
                                                   short* __restrict__ Wout) {
    const int t = blockIdx.x * 256 + threadIdx.x;
    const int code = Q[t] & 0xFFFF;
    const float4* g = (const float4*)(cb + (size_t)code * 8);
    const float4 v0 = g[0];
    const float4 v1 = g[1];
    short8 o;
    o[0] = f2bf(v0.x); o[1] = f2bf(v0.y); o[2] = f2bf(v0.z); o[3] = f2bf(v0.w);
    o[4] = f2bf(v1.x); o[5] = f2bf(v1.y); o[6] = f2bf(v1.z); o[7] = f2bf(v1.w);
    *(short8*)(Wout + (size_t)t * 8) = o;
}

// ---------------------------------------------------------------------------
// GEMM: C[B,M] = A[B,K] * W[M,K]^T — 256x256 tile, BK=64, 8 waves (2x4, wave
// tile 128x64), 16x16x32 MFMA, 2-deep LDS ring (128 KB), 4-phase register
// pipeline, 2 barriers/iter. A is staged FROM FP32 (fused cvt):
//   ph0: MFMA m0-3/h0 || read aH0[4-7] || issue 8 A-fp32 dwordx4 loads (t+1)
//   ph1: MFMA m4-7/h0 || read aH1[0-3], bH1[0-3] || 4 B-GLD(t+1)
//   ph2: MFMA m0-3/h1 || read aH1[4-7] ; cvt A->bf16 + 4 ds_write_b128 ;
//        vmcnt(0) ; lgkmcnt(0) ; barrier   (tile t+1 fully published)
//   ph3: MFMA m4-7/h1 || read next-tile ph0 frags from bufn ;
//        lgkmcnt(8) ; barrier   (all buf(t) reads drained)
// Hazard proof:
//  - visibility: A-writes (own ds_write, drained by lgkmcnt(0)) + B-GLDs
//    (drained by vmcnt(0)) complete before the ph2-end barrier; ph3's bufn
//    reads follow it.
//  - overwrite: writes into buf((t+1)&1) (A ds_write at ph2, B GLD at ph1)
//    occur after iter t-1's final barrier, which followed lgkmcnt(8) draining
//    every read of that buffer (ph3's 8 bufn reads are the newest 8).
//  - prologue: stage tile 0 (loads+cvt+writes), vmcnt(0)+lgkm(0)+barrier.
// LDS swizzle (BK=64 rows = 8 x 16B units): stored unit = u ^ (row&7);
// GLOBAL source / A-load source inverse-swizzled (both-sides rule).
// ---------------------------------------------------------------------------
#define BM 256
#define BN 256
#define BK 64
#define NT (K_DIM / BK)   // 64

#define GLD(src, dst) \
    __builtin_amdgcn_global_load_lds( \
        (const __attribute__((address_space(1))) void*)(src), \
        (__attribute__((address_space(3))) void*)(dst), 16, 0, 0)

#define MFMA(a, b, c) __builtin_amdgcn_mfma_f32_16x16x32_bf16(a, b, c, 0, 0, 0)

__global__ __launch_bounds__(512, 2) void gemm_bt_kernel(const float* __restrict__ Af,
                                                         const short* __restrict__ Wd,
                                                         float* __restrict__ C) {
    __shared__ short lds[2 * 32768];   // 2 bufs x (A 32KB | B 32KB) = 128 KB

    const int tid  = threadIdx.x;
    const int wave = tid >> 6;
    const int lane = tid & 63;

    // XCD-chunked swizzle: 256 blocks -> 8 XCDs, each a 4x8 block chunk
    const int bid = blockIdx.x;
    const int xcd = bid & 7;
    const int s   = bid >> 3;
    const int by  = (xcd >> 1) * 4 + (s >> 3);
    const int bx  = (xcd & 1) * 8 + (s & 7);

    const int rowBase = by * BM;
    const int colBase = bx * BN;

    const int wr = wave >> 2;                 // 0..1  (128-row half)
    const int wc = wave & 3;                  // 0..3  (64-col quarter)

    // ---- staging: thread covers rows (tid>>3)+c*64, stored unit tid&7 ----
    const int rA0 = tid >> 3;                 // 0..63
    const int uu  = (tid & 7) ^ (rA0 & 7);    // inverse-swizzled logical unit
    const int stOff = rA0 * 64 + (tid & 7) * 8;   // shorts; +c*4096
    const float* aSrcF = Af + (size_t)(rowBase + rA0) * K_DIM + uu * 8;
    const short* bSrcB = Wd + (size_t)(colBase + rA0) * K_DIM + uu * 8;

    // ---- fragment read offsets (shorts) ----
    const int l15 = lane & 15;
    const int l4  = lane >> 4;
    const int uk0 = ((l4 ^ (l15 & 7))) * 8;   // h=0 stored-unit offset
    const int uk1 = uk0 ^ 32;                 // h=1 (unit XOR 4)
    const int aRow = (wr * 128 + l15) * 64;           // + m*1024 + ukh
    const int bRow = 16384 + (wc * 64 + l15) * 64;    // + n*1024 + ukh

    f32x4 acc[8][4] = {};
    short8 aC[4], bC[4];      // ph0 operands (loop-carried, written at ph3)
    float4 fa[4][2];          // in-flight A fp32 (tile t+1)

    // ---- prologue: stage tile 0 into buf0, publish, read ph0 frags ----
#pragma unroll
    for (int c = 0; c < 4; ++c) {
        const float4* p = (const float4*)(aSrcF + (size_t)c * (64 * K_DIM));
        fa[c][0] = p[0];
        fa[c][1] = p[1];
    }
#pragma unroll
    for (int c = 0; c < 4; ++c)
        GLD(bSrcB + c * (64 * K_DIM), &lds[16384 + c * 4096 + stOff]);
#pragma unroll
    for (int c = 0; c < 4; ++c) {
        short8 w;
        w[0] = f2bf(fa[c][0].x); w[1] = f2bf(fa[c][0].y);
        w[2] = f2bf(fa[c][0].z); w[3] = f2bf(fa[c][0].w);
        w[4] = f2bf(fa[c][1].x); w[5] = f2bf(fa[c][1].y);
        w[6] = f2bf(fa[c][1].z); w[7] = f2bf(fa[c][1].w);
        *(short8*)&lds[c * 4096 + stOff] = w;
    }
    asm volatile("s_waitcnt vmcnt(0)" ::: "memory");
    asm volatile("s_waitcnt lgkmcnt(0)" ::: "memory");
    __builtin_amdgcn_s_barrier();
#pragma unroll
    for (int m = 0; m < 4; ++m) aC[m] = *(const short8*)&lds[aRow + m * 1024 + uk0];
#pragma unroll
    for (int n = 0; n < 4; ++n) bC[n] = *(const short8*)&lds[bRow + n * 1024 + uk0];

    for (int t = 0; t < NT; ++t) {
        const int buf  = (t & 1) * 32768;
        const int bufn = buf ^ 32768;
        const size_t kpre = (size_t)(((t + 1 < NT) ? (t + 1) : (NT - 1)) * BK);

        // ---- ph0: MFMA m0-3 x h0 ; read aH0[4-7] ; issue 8 A-fp32 loads ----
        short8 a1h0[4];
#pragma unroll
        for (int m = 0; m < 4; ++m)
            a1h0[m] = *(const short8*)&lds[buf + aRow + (m + 4) * 1024 + uk0];
#pragma unroll
        for (int c = 0; c < 4; ++c) {
            const float4* p = (const float4*)(aSrcF + kpre + (size_t)c * (64 * K_DIM));
            fa[c][0] = p[0];
            fa[c][1] = p[1];
        }
        __builtin_amdgcn_s_setprio(1);
#pragma unroll
        for (int m = 0; m < 4; ++m)
#pragma unroll
            for (int n = 0; n < 4; ++n)
                acc[m][n] = MFMA(aC[m], bC[n], acc[m][n]);
        __builtin_amdgcn_s_setprio(0);

        // ---- ph1: MFMA m4-7 x h0 ; read aH1[0-3], bH1[0-3] ; 4 B-GLD ----
        short8 a0h1[4], b1[4];
#pragma unroll
        for (int m = 0; m < 4; ++m)
            a0h1[m] = *(const short8*)&lds[buf + aRow + m * 1024 + uk1];
#pragma unroll
        for (int n = 0; n < 4; ++n)
            b1[n] = *(const short8*)&lds[buf + bRow + n * 1024 + uk1];
#pragma unroll
        for (int c = 0; c < 4; ++c)
            GLD(bSrcB + kpre + c * (64 * K_DIM), &lds[bufn + 16384 + c * 4096 + stOff]);
        __builtin_amdgcn_s_setprio(1);
#pragma unroll
        for (int m = 0; m < 4; ++m)
#pragma unroll
            for (int n = 0; n < 4; ++n)
                acc[m + 4][n] = MFMA(a1h0[m], bC[n], acc[m + 4][n]);
        __builtin_amdgcn_s_setprio(0);

        // ---- ph2: MFMA m0-3 x h1 ; read aH1[4-7] ; cvt+ds_write A ;
        //           vmcnt(0)+lgkm(0)+barrier ----
        short8 a1h1[4];
#pragma unroll
        for (int m = 0; m < 4; ++m)
            a1h1[m] = *(const short8*)&lds[buf + aRow + (m + 4) * 1024 + uk1];
#pragma unroll
        for (int c = 0; c < 4; ++c) {
            short8 w;
            w[0] = f2bf(fa[c][0].x); w[1] = f2bf(fa[c][0].y);
            w[2] = f2bf(fa[c][0].z); w[3] = f2bf(fa[c][0].w);
            w[4] = f2bf(fa[c][1].x); w[5] = f2bf(fa[c][1].y);
            w[6] = f2bf(fa[c][1].z); w[7] = f2bf(fa[c][1].w);
            *(short8*)&lds[bufn + c * 4096 + stOff] = w;
        }
        __builtin_amdgcn_s_setprio(1);
#pragma unroll
        for (int m = 0; m < 4; ++m)
#pragma unroll
            for (int n = 0; n < 4; ++n)
                acc[m][n] = MFMA(a0h1[m], b1[n], acc[m][n]);
        __builtin_amdgcn_s_setprio(0);
        asm volatile("s_waitcnt vmcnt(0)" ::: "memory");   // B-GLDs landed
        asm volatile("s_waitcnt lgkmcnt(0)" ::: "memory"); // A ds_writes done
        __builtin_amdgcn_s_barrier();

        // ---- ph3: MFMA m4-7 x h1 ; read next-tile ph0 frags from bufn ----
#pragma unroll
        for (int m = 0; m < 4; ++m)
            aC[m] = *(const short8*)&lds[bufn + aRow + m * 1024 + uk0];
#pragma unroll
        for (int n = 0; n < 4; ++n)
            bC[n] = *(const short8*)&lds[bufn + bRow + n * 1024 + uk0];
        __builtin_amdgcn_s_setprio(1);
#pragma unroll
        for (int m = 0; m < 4; ++m)
#pragma unroll
            for (int n = 0; n < 4; ++n)
                acc[m + 4][n] = MFMA(a1h1[m], b1[n], acc[m + 4][n]);
        __builtin_amdgcn_s_setprio(0);
        asm volatile("s_waitcnt lgkmcnt(8)" ::: "memory"); // buf(t) reads drained
        __builtin_amdgcn_s_barrier();
    }

    // epilogue: C/D layout col = lane&15, row = (lane>>4)*4 + reg
    const int r0 = rowBase + wr * 128 + l4 * 4;
    const int c0 = colBase + wc * 64 + l15;
#pragma unroll
    for (int m = 0; m < 8; ++m)
#pragma unroll
        for (int n = 0; n < 4; ++n) {
            float* cp = C + (size_t)(r0 + m * 16) * M_DIM + (c0 + n * 16);
#pragma unroll
            for (int reg = 0; reg < 4; ++reg)
                cp[(size_t)reg * M_DIM] = acc[m][n][reg];
        }
}

// ---------------------------------------------------------------------------
extern "C" void kernel_launch(void* const* d_in, const int* in_sizes, int n_in,
                              void* d_out, int out_size, void* d_ws, size_t ws_size,
                              hipStream_t stream) {
    const float* inp  = (const float*)d_in[0];
    const int*   qidx = (const int*)d_in[1];
    const float* cb   = (const float*)d_in[2];
    float* out = (float*)d_out;

    short* Wb = (short*)d_ws;

    const int n_codes = M_DIM * NCODE;           // 2,097,152
    prep_kernel<<<n_codes / 256, 256, 0, stream>>>(qidx, cb, Wb);

    gemm_bt_kernel<<<256, 512, 0, stream>>>(inp, Wb, out);
}

// Round 10
// 135.800 us; speedup vs baseline: 1.2257x; 1.2257x over previous
//
#include <hip/hip_runtime.h>
#include <hip/hip_bf16.h>

#define B_DIM 4096
#define M_DIM 4096
#define K_DIM 4096
#define NCODE 512

typedef __attribute__((ext_vector_type(4))) float f32x4;
typedef __attribute__((ext_vector_type(8))) short short8;

__device__ __forceinline__ unsigned short f2bf(float f) {
    union { float f; unsigned u; } c; c.f = f;
    unsigned u = c.u;
    return (unsigned short)((u + 0x7FFFu + ((u >> 16) & 1u)) >> 16);
}

// ---------------------------------------------------------------------------
// Fused prep: blocks [0,8192) dequantize codes -> bf16 W; [8192,16384) cvt A.
// ---------------------------------------------------------------------------
__global__ __launch_bounds__(256) void prep_kernel(const int* __restrict__ Q,
                                                   const float* __restrict__ cb,
                                                   short* __restrict__ Wout,
                                                   const float* __restrict__ in,
                                                   short* __restrict__ Ab) {
    const int b = blockIdx.x;
    if (b < 8192) {
        const int t = b * 256 + threadIdx.x;
        const int code = Q[t] & 0xFFFF;
        const float4* g = (const float4*)(cb + (size_t)code * 8);
        const float4 v0 = g[0];
        const float4 v1 = g[1];
        short8 o;
        o[0] = f2bf(v0.x); o[1] = f2bf(v0.y); o[2] = f2bf(v0.z); o[3] = f2bf(v0.w);
        o[4] = f2bf(v1.x); o[5] = f2bf(v1.y); o[6] = f2bf(v1.z); o[7] = f2bf(v1.w);
        *(short8*)(Wout + (size_t)t * 8) = o;
    } else {
        const int t = (b - 8192) * 256 + threadIdx.x;
        const float4* p = (const float4*)(in + (size_t)t * 8);
        const float4 v0 = p[0];
        const float4 v1 = p[1];
        short8 o;
        o[0] = f2bf(v0.x); o[1] = f2bf(v0.y); o[2] = f2bf(v0.z); o[3] = f2bf(v0.w);
        o[4] = f2bf(v1.x); o[5] = f2bf(v1.y); o[6] = f2bf(v1.z); o[7] = f2bf(v1.w);
        *(short8*)(Ab + (size_t)t * 8) = o;
    }
}

// ---------------------------------------------------------------------------
// GEMM: C[B,M] = A[B,K] * W[M,K]^T — 256x256 tile, BK=64, 8 waves (2x4, wave
// tile 128x64), 16x16x32 MFMA, 4-phase register pipeline (phase p reads phase
// p+1's frags), A 2-deep ring (64 KB) + B 3-DEEP ring (96 KB) = 160 KB LDS.
// All VMEM waits are COUNT-POSITIVE (never drain to 0 in the main loop):
//   ph0: MFMA m0-3/h0 || read aH0[4-7] || 4 A-GLD(t+1) -> abuf((t+1)&1)
//   ph1: MFMA m4-7/h0 || read aH1[0-3], bH1[0-3] || 4 B-GLD(t+2) -> bbuf((t+2)%3)
//   ph2: MFMA m0-3/h1 || read aH1[4-7] ; vmcnt(4) ; barrier
//        [steady state: outstanding B(t+1)4,A(t+1)4,B(t+2)4=12 -> drain 8
//         oldest = B(t+1),A(t+1); B(t+2) stays in flight. B(t+1) was issued
//         ~1.5 iters (~6000 cy) earlier, A(t+1) ~2000 cy earlier: wait ~free.]
//   ph3: MFMA m4-7/h1 || read next-iter ph0 frags (abuf((t+1)&1), bbuf((t+1)%3))
//        lgkmcnt(8) ; barrier
// Hazard audit:
//  - visibility: tile t+1 (A and B) drained by ph2(t)'s vmcnt(4)+barrier;
//    ph3(t)'s reads of it follow that barrier. Prologue: A(0),B(0),B(1) issued
//    (12), vmcnt(4) drains A(0),B(0); barrier; read tile-0 ph0 frags.
//  - overwrite A: A(t+2)-GLD -> abuf(t&1) issues at iter t+1 ph0, after iter
//    t's final barrier; abuf(t&1) reads (ph0/ph1/ph2 of iter t) are all older
//    than ph3's 8 reads, hence drained by iter t's lgkmcnt(8). ph3's own
//    pending reads target abuf((t+1)&1)/bbuf((t+1)%3) — disjoint.
//  - overwrite B: B(t+3)-GLD -> bbuf(t%3) issues at iter t+1 ph1; last read
//    of bbuf(t%3) is iter t ph1 (b1), drained by iter t's lgkmcnt(8)+barrier.
// LDS swizzle (BK=64 rows = 8 x 16B units): stored unit = u ^ (row&7);
// GLOBAL source inverse-swizzled (both-sides rule) -> conflict-free b128.
// ---------------------------------------------------------------------------
#define BM 256
#define BN 256
#define BK 64
#define NT (K_DIM / BK)   // 64

// LDS layout in shorts: A bufs @ 0, 16384 ; B bufs @ 32768 + bi*16384
#define ABUF(i) ((i) * 16384)
#define BBUF(i) (32768 + (i) * 16384)

#define GLD(src, dst) \
    __builtin_amdgcn_global_load_lds( \
        (const __attribute__((address_space(1))) void*)(src), \
        (__attribute__((address_space(3))) void*)(dst), 16, 0, 0)

#define MFMA(a, b, c) __builtin_amdgcn_mfma_f32_16x16x32_bf16(a, b, c, 0, 0, 0)

__global__ __launch_bounds__(512, 2) void gemm_bt_kernel(const short* __restrict__ A,
                                                         const short* __restrict__ Wd,
                                                         float* __restrict__ C) {
    __shared__ short lds[81920];   // 160 KB: A 2x32KB + B 3x32KB

    const int tid  = threadIdx.x;
    const int wave = tid >> 6;
    const int lane = tid & 63;

    // XCD-chunked swizzle: 256 blocks -> 8 XCDs, each a 4x8 block chunk
    const int bid = blockIdx.x;
    const int xcd = bid & 7;
    const int s   = bid >> 3;
    const int by  = (xcd >> 1) * 4 + (s >> 3);
    const int bx  = (xcd & 1) * 8 + (s & 7);

    const int rowBase = by * BM;
    const int colBase = bx * BN;

    const int wr = wave >> 2;                 // 0..1  (128-row half)
    const int wc = wave & 3;                  // 0..3  (64-col quarter)

    // ---- staging: thread covers rows (tid>>3)+c*64, stored unit tid&7 ----
    const int rA0 = tid >> 3;                 // 0..63
    const int uu  = (tid & 7) ^ (rA0 & 7);    // inverse-swizzled logical unit
    const int stOff = rA0 * 64 + (tid & 7) * 8;   // shorts; +c*4096
    const short* aSrcB = A  + (size_t)(rowBase + rA0) * K_DIM + uu * 8;
    const short* bSrcB = Wd + (size_t)(colBase + rA0) * K_DIM + uu * 8;

    // ---- fragment read offsets (shorts, within a buffer) ----
    const int l15 = lane & 15;
    const int l4  = lane >> 4;
    const int uk0 = ((l4 ^ (l15 & 7))) * 8;   // h=0 stored-unit offset
    const int uk1 = uk0 ^ 32;                 // h=1 (unit XOR 4)
    const int aRow = (wr * 128 + l15) * 64;   // + m*1024 + ukh
    const int bRow = (wc * 64 + l15) * 64;    // + n*1024 + ukh

    f32x4 acc[8][4] = {};
    short8 aC[4], bC[4];      // ph0 operands (loop-carried, written at ph3)

    // ---- prologue: stage A(0)->abuf0, B(0)->bbuf0, B(1)->bbuf1 ----
#pragma unroll
    for (int c = 0; c < 4; ++c)
        GLD(aSrcB + c * (64 * K_DIM), &lds[ABUF(0) + c * 4096 + stOff]);
#pragma unroll
    for (int c = 0; c < 4; ++c)
        GLD(bSrcB + c * (64 * K_DIM), &lds[BBUF(0) + c * 4096 + stOff]);
#pragma unroll
    for (int c = 0; c < 4; ++c)
        GLD(bSrcB + BK + c * (64 * K_DIM), &lds[BBUF(1) + c * 4096 + stOff]);
    asm volatile("s_waitcnt vmcnt(4)" ::: "memory");   // A(0),B(0) landed
    __builtin_amdgcn_s_barrier();
#pragma unroll
    for (int m = 0; m < 4; ++m)
        aC[m] = *(const short8*)&lds[ABUF(0) + aRow + m * 1024 + uk0];
#pragma unroll
    for (int n = 0; n < 4; ++n)
        bC[n] = *(const short8*)&lds[BBUF(0) + bRow + n * 1024 + uk0];

    int bcur = 0;                 // t % 3
    for (int t = 0; t < NT; ++t) {
        const int abuf  = ABUF(t & 1);
        const int abufn = ABUF((t + 1) & 1);
        const int bbuf  = BBUF(bcur);
        const int bnx1  = (bcur + 1 < 3) ? (bcur + 1) : 0;   // (t+1)%3
        const int bnx2  = (bnx1 + 1 < 3) ? (bnx1 + 1) : 0;   // (t+2)%3
        const int bbufn = BBUF(bnx1);
        const size_t kpre1 = (size_t)(((t + 1 < NT) ? (t + 1) : (NT - 1)) * BK);
        const size_t kpre2 = (size_t)(((t + 2 < NT) ? (t + 2) : (NT - 1)) * BK);

        // ---- ph0: MFMA m0-3 x h0 ; read aH0[4-7] ; 4 A-GLD(t+1) ----
        short8 a1h0[4];
#pragma unroll
        for (int m = 0; m < 4; ++m)
            a1h0[m] = *(const short8*)&lds[abuf + aRow + (m + 4) * 1024 + uk0];
#pragma unroll
        for (int c = 0; c < 4; ++c)
            GLD(aSrcB + kpre1 + c * (64 * K_DIM), &lds[abufn + c * 4096 + stOff]);
        __builtin_amdgcn_s_setprio(1);
#pragma unroll
        for (int m = 0; m < 4; ++m)
#pragma unroll
            for (int n = 0; n < 4; ++n)
                acc[m][n] = MFMA(aC[m], bC[n], acc[m][n]);
        __builtin_amdgcn_s_setprio(0);

        // ---- ph1: MFMA m4-7 x h0 ; read aH1[0-3], bH1[0-3] ; 4 B-GLD(t+2) ----
        short8 a0h1[4], b1[4];
#pragma unroll
        for (int m = 0; m < 4; ++m)
            a0h1[m] = *(const short8*)&lds[abuf + aRow + m * 1024 + uk1];
#pragma unroll
        for (int n = 0; n < 4; ++n)
            b1[n] = *(const short8*)&lds[bbuf + bRow + n * 1024 + uk1];
#pragma unroll
        for (int c = 0; c < 4; ++c)
            GLD(bSrcB + kpre2 + c * (64 * K_DIM),
                &lds[BBUF(bnx2) + c * 4096 + stOff]);
        __builtin_amdgcn_s_setprio(1);
#pragma unroll
        for (int m = 0; m < 4; ++m)
#pragma unroll
            for (int n = 0; n < 4; ++n)
                acc[m + 4][n] = MFMA(a1h0[m], bC[n], acc[m + 4][n]);
        __builtin_amdgcn_s_setprio(0);

        // ---- ph2: MFMA m0-3 x h1 ; read aH1[4-7] ; vmcnt(4)+barrier ----
        short8 a1h1[4];
#pragma unroll
        for (int m = 0; m < 4; ++m)
            a1h1[m] = *(const short8*)&lds[abuf + aRow + (m + 4) * 1024 + uk1];
        __builtin_amdgcn_s_setprio(1);
#pragma unroll
        for (int m = 0; m < 4; ++m)
#pragma unroll
            for (int n = 0; n < 4; ++n)
                acc[m][n] = MFMA(a0h1[m], b1[n], acc[m][n]);
        __builtin_amdgcn_s_setprio(0);
        asm volatile("s_waitcnt vmcnt(4)" ::: "memory");   // tile t+1 landed
        __builtin_amdgcn_s_barrier();

        // ---- ph3: MFMA m4-7 x h1 ; read next-iter ph0 frags ----
#pragma unroll
        for (int m = 0; m < 4; ++m)
            aC[m] = *(const short8*)&lds[abufn + aRow + m * 1024 + uk0];
#pragma unroll
        for (int n = 0; n < 4; ++n)
            bC[n] = *(const short8*)&lds[bbufn + bRow + n * 1024 + uk0];
        __builtin_amdgcn_s_setprio(1);
#pragma unroll
        for (int m = 0; m < 4; ++m)
#pragma unroll
            for (int n = 0; n < 4; ++n)
                acc[m + 4][n] = MFMA(a1h1[m], b1[n], acc[m + 4][n]);
        __builtin_amdgcn_s_setprio(0);
        asm volatile("s_waitcnt lgkmcnt(8)" ::: "memory"); // old-buffer reads drained
        __builtin_amdgcn_s_barrier();

        bcur = bnx1;
    }

    // epilogue: C/D layout col = lane&15, row = (lane>>4)*4 + reg
    const int r0 = rowBase + wr * 128 + l4 * 4;
    const int c0 = colBase + wc * 64 + l15;
#pragma unroll
    for (int m = 0; m < 8; ++m)
#pragma unroll
        for (int n = 0; n < 4; ++n) {
            float* cp = C + (size_t)(r0 + m * 16) * M_DIM + (c0 + n * 16);
#pragma unroll
            for (int reg = 0; reg < 4; ++reg)
                cp[(size_t)reg * M_DIM] = acc[m][n][reg];
        }
}

// ---------------------------------------------------------------------------
extern "C" void kernel_launch(void* const* d_in, const int* in_sizes, int n_in,
                              void* d_out, int out_size, void* d_ws, size_t ws_size,
                              hipStream_t stream) {
    const float* inp  = (const float*)d_in[0];
    const int*   qidx = (const int*)d_in[1];
    const float* cb   = (const float*)d_in[2];
    float* out = (float*)d_out;

    short* Wb = (short*)d_ws;
    short* Ab = Wb + (size_t)M_DIM * K_DIM;

    prep_kernel<<<16384, 256, 0, stream>>>(qidx, cb, Wb, inp, Ab);

    gemm_bt_kernel<<<256, 512, 0, stream>>>(Ab, Wb, out);
}